// Round 9
// baseline (950.112 us; speedup 1.0000x reference)
//
#include <hip/hip_runtime.h>

// GRU scan: B=2048, T=2048, D=3, H=32. out[b,t] = h_new[b,t][0].
// Round-11: 1 seq/wave + register h => 2 waves/SIMD TLP + low pressure.
// R10 post-mortem: at 1 wave/SIMD every chain stall is exposed (no TLP),
// and 96 weight floats/lane forced AGPR shuffling (~+100 real inst/step,
// VALUBusy-counted). This round: K-split 2 lanes/unit, 1 seq/wave:
//  - rows r=0..3 (16 lanes): carried h-block cblk=gray(r), unit
//    u=16*(r&1)+li, kbase=16*cblk (carried block == k-block, forced).
//  - own-block all-gather: 15 DPP row_ror (weights pre-permuted, dir
//    probed). K-half combine: partners are lane^32 -> 3 permlane32_swap.
//    h_prev for rows 2,3: 1 more swap32 + cndmask. Carry-fix: 1
//    permlane16_swap + cndmask (runtime sel; bperm fallback).
//  - w_ih/bias for r,z zeroed on cblk1 lanes at load time -> input
//    projections ride the exchanged half-sums at zero extra cost.
//  - 48 weight floats/lane -> fits comfortably; ~103 inst/step/wave;
//    grid 2048 x 64, __launch_bounds__(64,2) = 2 waves/SIMD.

#define GRU_B 2048
#define GRU_T 2048
#define GRU_D 3
#define GRU_H 32
#define CHUNK 32

typedef unsigned int uint2v __attribute__((ext_vector_type(2)));

__device__ __forceinline__ float fast_sigmoid(float x) {
    float e = __expf(-x);                    // v_mul(log2e)+v_exp
    return __builtin_amdgcn_rcpf(1.0f + e);  // e=inf -> 0 (correct limit)
}
__device__ __forceinline__ float fast_tanh(float x) {
    float e = __expf(2.0f * x);              // overflow -> inf -> tanh=1
    return 1.0f - 2.0f * __builtin_amdgcn_rcpf(e + 1.0f);
}
__device__ __forceinline__ float bperm(float v, int baddr) {
    return __int_as_float(__builtin_amdgcn_ds_bpermute(baddr, __float_as_int(v)));
}

// DPP row_ror:N = 0x120+N; all rows/banks, no bound ctrl.
#define DPPF(v, CTRL) __int_as_float(__builtin_amdgcn_update_dpp( \
    0, __float_as_int(v), (CTRL), 0xF, 0xF, false))

template<bool SEL>
__device__ __forceinline__ float swap32(float v) {
    uint2v r = __builtin_amdgcn_permlane32_swap(
        __float_as_uint(v), __float_as_uint(v), false, false);
    return __uint_as_float(SEL ? r.x : r.y);
}

#if __has_builtin(__builtin_amdgcn_permlane16_swap)
#define HAVE_P16 1
#else
#define HAVE_P16 0
#endif

// ---------------- fast path: register h, 1 seq/wave ----------------
template<bool SEL32, bool USE16>
__device__ void gru_fast(
    const float* __restrict__ xp, float* __restrict__ ob,
    const float* __restrict__ w_ih, const float* __restrict__ w_hh,
    const float* __restrict__ bias, const float* __restrict__ bias_n,
    float* __restrict__ x_lds, int lane, int dir, bool sel16, int a16)
{
    const int li   = lane & 15;
    const int row  = lane >> 4;
    const int ublk = row & 1;                  // unit block
    const int cblk = (row ^ (row >> 1)) & 1;   // carried/k block (gray)
    const int u     = 16 * ublk + li;          // owned unit
    const int kbase = 16 * cblk;               // k-half this lane covers
    const bool c0   = (cblk == 0);

    // rotation-permuted weights: FMA j pairs DPP rotation j.
    float wrr[16], wzz[16], wnn[16];
#pragma unroll
    for (int j = 0; j < 16; ++j) {
        const int kk = kbase + ((li + dir * j + 16) & 15);
        wrr[j] = w_hh[(size_t)u * GRU_H + kk];
        wzz[j] = w_hh[(size_t)(GRU_H + u) * GRU_H + kk];
        wnn[j] = w_hh[(size_t)(2 * GRU_H + u) * GRU_H + kk];
    }
    // r,z input projections only on cblk0 lanes (ride the exchange);
    // n projection full on all lanes (needed outside the h-dot).
    float wir[GRU_D], wiz[GRU_D], win[GRU_D];
#pragma unroll
    for (int d = 0; d < GRU_D; ++d) {
        wir[d] = c0 ? w_ih[(size_t)u * GRU_D + d] : 0.0f;
        wiz[d] = c0 ? w_ih[(size_t)(GRU_H + u) * GRU_D + d] : 0.0f;
        win[d] = w_ih[(size_t)(2 * GRU_H + u) * GRU_D + d];
    }
    const float bR = c0 ? bias[u] : 0.0f;
    const float bZ = c0 ? bias[GRU_H + u] : 0.0f;
    const float bN = bias[2 * GRU_H + u] + bias_n[u];

    float h = 0.0f;  // carried h[kbase + li]
    // chunk-0 global prefetch (96 floats: 64 + 32 lanes)
    float xr0 = xp[lane];
    float xr1 = (lane < 32) ? xp[64 + lane] : 0.0f;

    for (int c = 0; c < GRU_T / CHUNK; ++c) {
        x_lds[lane] = xr0;
        if (lane < 32) x_lds[64 + lane] = xr1;
        if (c + 1 < GRU_T / CHUNK) {
            const size_t nb = (size_t)(c + 1) * (CHUNK * GRU_D);
            xr0 = xp[nb + lane];
            xr1 = (lane < 32) ? xp[nb + 64 + lane] : 0.0f;
        }
        // step-0 x (ordered behind staging in same-wave DS queue)
        float x0c = x_lds[0], x1c = x_lds[1], x2c = x_lds[2];
        float outreg = 0.0f;

#pragma unroll 8
        for (int s = 0; s < CHUNK; ++s) {
            const float aR = fmaf(wir[2], x2c, fmaf(wir[1], x1c, fmaf(wir[0], x0c, bR)));
            const float aZ = fmaf(wiz[2], x2c, fmaf(wiz[1], x1c, fmaf(wiz[0], x0c, bZ)));
            const float aN = fmaf(win[2], x2c, fmaf(win[1], x1c, fmaf(win[0], x0c, bN)));

            // next step's x (consumed next iteration; latency hidden)
            float x0n = x0c, x1n = x1c, x2n = x2c;
            if (s + 1 < CHUNK) {
                x0n = x_lds[3 * (s + 1) + 0];
                x1n = x_lds[3 * (s + 1) + 1];
                x2n = x_lds[3 * (s + 1) + 2];
            }

            // h_prev[u]: rows 2,3 carry the other block -> partner's h
            const float hx = swap32<SEL32>(h);
            const float hprev = (lane & 32) ? hx : h;

            // own-block all-gather: 15 DPP rotations
            float hr_[16];
            hr_[0] = h;
            hr_[1]  = DPPF(h, 0x121); hr_[2]  = DPPF(h, 0x122);
            hr_[3]  = DPPF(h, 0x123); hr_[4]  = DPPF(h, 0x124);
            hr_[5]  = DPPF(h, 0x125); hr_[6]  = DPPF(h, 0x126);
            hr_[7]  = DPPF(h, 0x127); hr_[8]  = DPPF(h, 0x128);
            hr_[9]  = DPPF(h, 0x129); hr_[10] = DPPF(h, 0x12A);
            hr_[11] = DPPF(h, 0x12B); hr_[12] = DPPF(h, 0x12C);
            hr_[13] = DPPF(h, 0x12D); hr_[14] = DPPF(h, 0x12E);
            hr_[15] = DPPF(h, 0x12F);

            // half-dots: 48 FMA, 2 chains per gate (8 deep)
            float r0 = aR, r1 = 0.f, z0 = aZ, z1 = 0.f, n0 = 0.f, n1 = 0.f;
#pragma unroll
            for (int j = 0; j < 8; ++j) {
                r0 = fmaf(wrr[j],     hr_[j],     r0);
                r1 = fmaf(wrr[j + 8], hr_[j + 8], r1);
                z0 = fmaf(wzz[j],     hr_[j],     z0);
                z1 = fmaf(wzz[j + 8], hr_[j + 8], z1);
                n0 = fmaf(wnn[j],     hr_[j],     n0);
                n1 = fmaf(wnn[j + 8], hr_[j + 8], n1);
            }
            const float rh = r0 + r1;
            const float zh = z0 + z1;
            const float nh = n0 + n1;
            // combine K-halves across lane^32 partners
            const float rs = rh + swap32<SEL32>(rh);
            const float zs = zh + swap32<SEL32>(zh);
            const float ns = nh + swap32<SEL32>(nh);

            const float rg = fast_sigmoid(rs);
            const float zg = fast_sigmoid(zs);
            const float ng = fast_tanh(fmaf(rg, ns, aN));
            const float hnew = fmaf(zg, hprev - ng, ng);  // (1-z)*n + z*h

            // out[t] = h_new[t][0]: lane0 (row0,li=0) computes unit 0
            const float h0 = __uint_as_float(
                (unsigned)__builtin_amdgcn_readfirstlane(__float_as_int(hnew)));
            if (lane == s) outreg = h0;

            // carry-fix: rows 2,3 swap with their lane^16 partner
            float fv;
            if constexpr (USE16) {
#if HAVE_P16
                uint2v f = __builtin_amdgcn_permlane16_swap(
                    __float_as_uint(hnew), __float_as_uint(hnew), false, false);
                fv = __uint_as_float(sel16 ? f.x : f.y);
#else
                fv = bperm(hnew, a16);
#endif
            } else {
                fv = bperm(hnew, a16);
            }
            h = (lane & 32) ? fv : hnew;

            x0c = x0n; x1c = x1n; x2c = x2n;
        }
        if (lane < CHUNK) ob[c * CHUNK + lane] = outreg;  // 128B coalesced
    }
}

// ------------- fallback (probe failure only): lanes 0-31, LDS h -------------
__device__ void gru_simple(
    const float* __restrict__ xp, float* __restrict__ ob,
    const float* __restrict__ w_ih, const float* __restrict__ w_hh,
    const float* __restrict__ bias, const float* __restrict__ bias_n,
    float* __restrict__ x_lds, float* __restrict__ h2, int lane)
{
    const int p = lane & 31;
    float wr[32], wz[32], wn[32];
#pragma unroll
    for (int k = 0; k < 32; ++k) {
        wr[k] = w_hh[(size_t)p * GRU_H + k];
        wz[k] = w_hh[(size_t)(GRU_H + p) * GRU_H + k];
        wn[k] = w_hh[(size_t)(2 * GRU_H + p) * GRU_H + k];
    }
    float wir[GRU_D], wiz[GRU_D], win[GRU_D];
#pragma unroll
    for (int d = 0; d < GRU_D; ++d) {
        wir[d] = w_ih[(size_t)p * GRU_D + d];
        wiz[d] = w_ih[(size_t)(GRU_H + p) * GRU_D + d];
        win[d] = w_ih[(size_t)(2 * GRU_H + p) * GRU_D + d];
    }
    const float bR = bias[p];
    const float bZ = bias[GRU_H + p];
    const float bN = bias[2 * GRU_H + p] + bias_n[p];

    float h = 0.0f;
    if (lane < 32) h2[lane] = 0.0f;
    __builtin_amdgcn_s_waitcnt(0xC07F);

    float xr0 = xp[lane];
    float xr1 = (lane < 32) ? xp[64 + lane] : 0.0f;

    for (int c = 0; c < GRU_T / CHUNK; ++c) {
        x_lds[lane] = xr0;
        if (lane < 32) x_lds[64 + lane] = xr1;
        if (c + 1 < GRU_T / CHUNK) {
            const size_t nb = (size_t)(c + 1) * (CHUNK * GRU_D);
            xr0 = xp[nb + lane];
            xr1 = (lane < 32) ? xp[nb + 64 + lane] : 0.0f;
        }
        float outreg = 0.0f;
#pragma unroll 4
        for (int s = 0; s < CHUNK; ++s) {
            const float x0 = x_lds[3 * s + 0];
            const float x1 = x_lds[3 * s + 1];
            const float x2 = x_lds[3 * s + 2];
            float4 hk[8];
            const float4* hv = (const float4*)h2;
#pragma unroll
            for (int q = 0; q < 8; ++q) hk[q] = hv[q];

            const float aR = fmaf(wir[2], x2, fmaf(wir[1], x1, fmaf(wir[0], x0, bR)));
            const float aZ = fmaf(wiz[2], x2, fmaf(wiz[1], x1, fmaf(wiz[0], x0, bZ)));
            const float aN = fmaf(win[2], x2, fmaf(win[1], x1, fmaf(win[0], x0, bN)));

            float r0 = aR, z0 = aZ, n0 = 0.f;
#pragma unroll
            for (int q = 0; q < 8; ++q) {
                const float4 v = hk[q];
                r0 = fmaf(wr[4*q+0], v.x, r0); r0 = fmaf(wr[4*q+1], v.y, r0);
                r0 = fmaf(wr[4*q+2], v.z, r0); r0 = fmaf(wr[4*q+3], v.w, r0);
                z0 = fmaf(wz[4*q+0], v.x, z0); z0 = fmaf(wz[4*q+1], v.y, z0);
                z0 = fmaf(wz[4*q+2], v.z, z0); z0 = fmaf(wz[4*q+3], v.w, z0);
                n0 = fmaf(wn[4*q+0], v.x, n0); n0 = fmaf(wn[4*q+1], v.y, n0);
                n0 = fmaf(wn[4*q+2], v.z, n0); n0 = fmaf(wn[4*q+3], v.w, n0);
            }
            const float rg = fast_sigmoid(r0);
            const float zg = fast_sigmoid(z0);
            const float ng = fast_tanh(fmaf(rg, n0, aN));
            const float hnew = fmaf(zg, h - ng, ng);
            const float h0 = __uint_as_float(
                (unsigned)__builtin_amdgcn_readfirstlane(__float_as_int(hnew)));
            if (lane == s) outreg = h0;
            h = hnew;
            if (lane < 32) h2[lane] = h;
        }
        if (lane < CHUNK) ob[c * CHUNK + lane] = outreg;
    }
}

__global__ __launch_bounds__(64, 2) void gru_scan_kernel(
    const float* __restrict__ inp, const float* __restrict__ w_ih,
    const float* __restrict__ w_hh, const float* __restrict__ bias,
    const float* __restrict__ bias_n, float* __restrict__ out)
{
    __shared__ __align__(16) float x_lds[CHUNK * GRU_D];  // 96 floats
    __shared__ __align__(16) float h2[GRU_H];             // fallback only

    const int lane = threadIdx.x;  // 0..63
    const size_t seq = blockIdx.x; // 1 seq per wave

    const float* xp = inp + seq * (size_t)(GRU_T * GRU_D);
    float*       ob = out + seq * (size_t)GRU_T;
    const int a16 = (lane ^ 16) << 2;

    // ---- one-time probes (ballot-verified, wave-uniform) ----
    int dir = 0;
    bool ok32 = false, sel32 = false, ok16 = false, sel16 = false;
    {
        const int li = lane & 15;
        const int d1 = __builtin_amdgcn_update_dpp(0, li, 0x121, 0xF, 0xF, false);
        if (__ballot(d1 == ((li + 1) & 15)) == ~0ULL)       dir = 1;
        else if (__ballot(d1 == ((li + 15) & 15)) == ~0ULL) dir = -1;

        const unsigned ul = (unsigned)lane;
        uint2v q = __builtin_amdgcn_permlane32_swap(ul, ul, false, false);
        const unsigned w32 = ul ^ 32u;
        const bool a = __ballot(q.x == w32) == ~0ULL;
        const bool b = __ballot(q.y == w32) == ~0ULL;
        ok32 = a || b; sel32 = a;

#if HAVE_P16
        uint2v q16 = __builtin_amdgcn_permlane16_swap(ul, ul, false, false);
        const unsigned w16 = ul ^ 16u;
        const bool a16ok = __ballot(q16.x == w16) == ~0ULL;
        const bool b16ok = __ballot(q16.y == w16) == ~0ULL;
        ok16 = a16ok || b16ok; sel16 = a16ok;
#endif
    }

    if (dir != 0 && ok32) {
        if (ok16) {
            if (sel32) gru_fast<true,  true >(xp, ob, w_ih, w_hh, bias, bias_n,
                                              x_lds, lane, dir, sel16, a16);
            else       gru_fast<false, true >(xp, ob, w_ih, w_hh, bias, bias_n,
                                              x_lds, lane, dir, sel16, a16);
        } else {
            if (sel32) gru_fast<true,  false>(xp, ob, w_ih, w_hh, bias, bias_n,
                                              x_lds, lane, dir, sel16, a16);
            else       gru_fast<false, false>(xp, ob, w_ih, w_hh, bias, bias_n,
                                              x_lds, lane, dir, sel16, a16);
        }
    } else {
        gru_simple(xp, ob, w_ih, w_hh, bias, bias_n, x_lds, h2, lane);
    }
}

extern "C" void kernel_launch(void* const* d_in, const int* in_sizes, int n_in,
                              void* d_out, int out_size, void* d_ws, size_t ws_size,
                              hipStream_t stream) {
    const float* inp    = (const float*)d_in[0];
    const float* w_ih   = (const float*)d_in[1];
    const float* w_hh   = (const float*)d_in[2];
    const float* bias   = (const float*)d_in[3];
    const float* bias_n = (const float*)d_in[4];
    float* out = (float*)d_out;

    dim3 grid(GRU_B);
    dim3 block(64);
    gru_scan_kernel<<<grid, block, 0, stream>>>(inp, w_ih, w_hh, bias, bias_n, out);
}

// Round 10
// 616.933 us; speedup vs baseline: 1.5401x; 1.5401x over previous
//
#include <hip/hip_runtime.h>

// GRU scan: B=2048, T=2048, D=3, H=32. out[b,t] = h_new[b,t][0].
// Round-12: v_fmac_f32_dpp fusion. Cross-round calibration (R6/R10/R11 all
// fit wall = inst x ~3.5-4cy + known stalls; R11's VALUBusy=101% = pipe
// saturated) says these kernels are VALU-ISSUE bound, not duty-bound.
// => minimize instructions/seq-step. R10 base (2 seq/wave, register h,
// 1 wave/SIMD), with the 96 fma + 31 rotation ops fused into 96
// v_fmac_f32_dpp (DPP on VOP2 src0): acc += rot_j(h) * w[j] is ONE inst.
//  - 6 asm blocks (gate x {own,other}), 16 chained fmacs each; 6
//    independent chains keep the pipe fed; s_nop 1 per block covers the
//    VALU-write->DPP-read hazard (compiler can't see into asm).
//  - other-block source = permlane32_swap(h) once (also reused for hprev).
//  - weight rotation-permutation identical to R10 (probed dir).
//  - probes fail -> verified LDS fallback (unchanged).

#define GRU_B 2048
#define GRU_T 2048
#define GRU_D 3
#define GRU_H 32
#define CHUNK 32
#define XPAD 104  // seq-B x base offset (bank +8)

typedef unsigned int uint2v __attribute__((ext_vector_type(2)));

__device__ __forceinline__ float fast_sigmoid(float x) {
    float e = __expf(-x);                    // v_mul(log2e)+v_exp
    return __builtin_amdgcn_rcpf(1.0f + e);  // e=inf -> 0 (correct limit)
}
__device__ __forceinline__ float fast_tanh(float x) {
    float e = __expf(2.0f * x);              // overflow -> inf -> tanh=1
    return 1.0f - 2.0f * __builtin_amdgcn_rcpf(e + 1.0f);
}
__device__ __forceinline__ float bperm(float v, int baddr) {
    return __int_as_float(__builtin_amdgcn_ds_bpermute(baddr, __float_as_int(v)));
}

template<bool SEL>
__device__ __forceinline__ float swap32(float v) {
    uint2v r = __builtin_amdgcn_permlane32_swap(
        __float_as_uint(v), __float_as_uint(v), false, false);
    return __uint_as_float(SEL ? r.x : r.y);
}

#if __has_builtin(__builtin_amdgcn_permlane16_swap)
#define HAVE_P16 1
#else
#define HAVE_P16 0
#endif

// acc += sum_j rot_j(HSRC) * W[j] : 16 fused v_fmac_f32_dpp (j=0 plain).
// s_nop 1 covers the VALU-write->DPP-read hazard for HSRC.
#define DOT16(ACC, HSRC, W) \
  asm("s_nop 1\n\t" \
      "v_fmac_f32 %0, %1, %2\n\t" \
      "v_fmac_f32_dpp %0, %1, %3 row_ror:1 row_mask:0xf bank_mask:0xf\n\t" \
      "v_fmac_f32_dpp %0, %1, %4 row_ror:2 row_mask:0xf bank_mask:0xf\n\t" \
      "v_fmac_f32_dpp %0, %1, %5 row_ror:3 row_mask:0xf bank_mask:0xf\n\t" \
      "v_fmac_f32_dpp %0, %1, %6 row_ror:4 row_mask:0xf bank_mask:0xf\n\t" \
      "v_fmac_f32_dpp %0, %1, %7 row_ror:5 row_mask:0xf bank_mask:0xf\n\t" \
      "v_fmac_f32_dpp %0, %1, %8 row_ror:6 row_mask:0xf bank_mask:0xf\n\t" \
      "v_fmac_f32_dpp %0, %1, %9 row_ror:7 row_mask:0xf bank_mask:0xf\n\t" \
      "v_fmac_f32_dpp %0, %1, %10 row_ror:8 row_mask:0xf bank_mask:0xf\n\t" \
      "v_fmac_f32_dpp %0, %1, %11 row_ror:9 row_mask:0xf bank_mask:0xf\n\t" \
      "v_fmac_f32_dpp %0, %1, %12 row_ror:10 row_mask:0xf bank_mask:0xf\n\t" \
      "v_fmac_f32_dpp %0, %1, %13 row_ror:11 row_mask:0xf bank_mask:0xf\n\t" \
      "v_fmac_f32_dpp %0, %1, %14 row_ror:12 row_mask:0xf bank_mask:0xf\n\t" \
      "v_fmac_f32_dpp %0, %1, %15 row_ror:13 row_mask:0xf bank_mask:0xf\n\t" \
      "v_fmac_f32_dpp %0, %1, %16 row_ror:14 row_mask:0xf bank_mask:0xf\n\t" \
      "v_fmac_f32_dpp %0, %1, %17 row_ror:15 row_mask:0xf bank_mask:0xf" \
      : "+v"(ACC) \
      : "v"(HSRC), "v"((W)[0]), "v"((W)[1]), "v"((W)[2]), "v"((W)[3]), \
        "v"((W)[4]), "v"((W)[5]), "v"((W)[6]), "v"((W)[7]), "v"((W)[8]), \
        "v"((W)[9]), "v"((W)[10]), "v"((W)[11]), "v"((W)[12]), "v"((W)[13]), \
        "v"((W)[14]), "v"((W)[15]))

// ---------------- fast path: register h, fused DPP-fmac ----------------
template<bool SEL32, bool USE16>
__device__ void gru_fast(
    const float* __restrict__ xp, float* __restrict__ ob,
    const float* __restrict__ w_ih, const float* __restrict__ w_hh,
    const float* __restrict__ bias, const float* __restrict__ bias_n,
    float* __restrict__ x_lds, int lane, int hf, int p, int dir,
    bool sel16, int a16)
{
    const int li = lane & 15;          // index within 16-row
    const int bb = 16 * (lane >> 5);   // own unit-block base (0 or 16)

    // weights permuted to rotation order: fmac j pairs row_ror:j.
    float wrO[16], wrX[16], wzO[16], wzX[16], wnO[16], wnX[16];
#pragma unroll
    for (int j = 0; j < 16; ++j) {
        const int kk = (li + dir * j + 16) & 15;
        const int kown = bb + kk;
        const int koth = (bb ^ 16) + kk;
        wrO[j] = w_hh[(size_t)p * GRU_H + kown];
        wrX[j] = w_hh[(size_t)p * GRU_H + koth];
        wzO[j] = w_hh[(size_t)(GRU_H + p) * GRU_H + kown];
        wzX[j] = w_hh[(size_t)(GRU_H + p) * GRU_H + koth];
        wnO[j] = w_hh[(size_t)(2 * GRU_H + p) * GRU_H + kown];
        wnX[j] = w_hh[(size_t)(2 * GRU_H + p) * GRU_H + koth];
    }
    float wir[GRU_D], wiz[GRU_D], win[GRU_D];
#pragma unroll
    for (int d = 0; d < GRU_D; ++d) {
        wir[d] = w_ih[(size_t)p * GRU_D + d];
        wiz[d] = w_ih[(size_t)(GRU_H + p) * GRU_D + d];
        win[d] = w_ih[(size_t)(2 * GRU_H + p) * GRU_D + d];
    }
    const float bR = bias[p];
    const float bZ = bias[GRU_H + p];
    const float bN = bias[2 * GRU_H + p] + bias_n[p];

    float* xw = x_lds + XPAD * hf;
    const float* xr = x_lds + XPAD * hf;

    float h = 0.0f;
    // global prefetch of chunk 0 (chunk-ahead; HBM-safe)
    float xa = xp[p], xb = xp[32 + p], xc = xp[64 + p];

    for (int c = 0; c < GRU_T / CHUNK; ++c) {
        // stage current chunk (regs -> LDS); prefetch next chunk (global)
        xw[p] = xa; xw[32 + p] = xb; xw[64 + p] = xc;
        if (c + 1 < GRU_T / CHUNK) {
            const size_t nb = (size_t)(c + 1) * (CHUNK * GRU_D);
            xa = xp[nb + p]; xb = xp[nb + 32 + p]; xc = xp[nb + 64 + p];
        }
        // step-0 x (ordered behind staging in the same-wave DS queue)
        float x0c = xr[0], x1c = xr[1], x2c = xr[2];
        float outreg = 0.0f;

#pragma unroll 8
        for (int s = 0; s < CHUNK; ++s) {
            // projections consume x prefetched one step ago (no stall)
            const float aR = fmaf(wir[2], x2c, fmaf(wir[1], x1c, fmaf(wir[0], x0c, bR)));
            const float aZ = fmaf(wiz[2], x2c, fmaf(wiz[1], x1c, fmaf(wiz[0], x0c, bZ)));
            const float aN = fmaf(win[2], x2c, fmaf(win[1], x1c, fmaf(win[0], x0c, bN)));

            // issue next step's x reads (consumed next iteration)
            float x0n = x0c, x1n = x1c, x2n = x2c;
            if (s + 1 < CHUNK) {
                x0n = xr[3 * (s + 1) + 0];
                x1n = xr[3 * (s + 1) + 1];
                x2n = xr[3 * (s + 1) + 2];
            }

            // one cross-block exchange; reused for hprev and the X-dots
            const float hsw = swap32<SEL32>(h);
            const float hprev = (lane & 32) ? hsw : h;

            // 96 fused fmac-dpp: 6 independent 16-chains
            float accOr = aR,  accXr = 0.0f;
            float accOz = aZ,  accXz = 0.0f;
            float accOn = 0.f, accXn = 0.0f;
            DOT16(accOr, h,   wrO);
            DOT16(accXr, hsw, wrX);
            DOT16(accOz, h,   wzO);
            DOT16(accXz, hsw, wzX);
            DOT16(accOn, h,   wnO);
            DOT16(accXn, hsw, wnX);

            const float rs = accOr + accXr;
            const float zs = accOz + accXz;
            const float ns = accOn + accXn;

            const float rg = fast_sigmoid(rs);
            const float zg = fast_sigmoid(zs);
            const float ng = fast_tanh(fmaf(rg, ns, aN));
            const float hnew = fmaf(zg, hprev - ng, ng);  // (1-z)*n + z*h

            // capture out[t]=h_new[t][0] (VALU broadcast, off-chain):
            // lane 0 = seq A unit 0, lane 16 = seq B unit 0.
            const float h0A = __uint_as_float(
                (unsigned)__builtin_amdgcn_readfirstlane(__float_as_int(hnew)));
            const float h0B = __uint_as_float(
                (unsigned)__builtin_amdgcn_readlane(__float_as_int(hnew), 16));
            const float want = hf ? h0B : h0A;
            if (p == s) outreg = want;

            // carry-fix: upper lanes exchange with lane^16 partner
            float fv;
            if constexpr (USE16) {
#if HAVE_P16
                uint2v f = __builtin_amdgcn_permlane16_swap(
                    __float_as_uint(hnew), __float_as_uint(hnew), false, false);
                fv = __uint_as_float(sel16 ? f.x : f.y);
#else
                fv = bperm(hnew, a16);
#endif
            } else {
                fv = bperm(hnew, a16);
            }
            h = (lane & 32) ? fv : hnew;

            x0c = x0n; x1c = x1n; x2c = x2n;
        }
        ob[c * CHUNK + p] = outreg;  // 64B runs per 16-lane group
    }
}

// ---------------- fallback: LDS h exchange (probe failure only) ----------------
__device__ void gru_lds(
    const float* __restrict__ xp, float* __restrict__ ob,
    const float* __restrict__ w_ih, const float* __restrict__ w_hh,
    const float* __restrict__ bias, const float* __restrict__ bias_n,
    float* __restrict__ x_lds, float* __restrict__ out_stage,
    float* __restrict__ h2, int lane, int hf, int p)
{
    float wr[32], wz[32], wn[32];
#pragma unroll
    for (int k = 0; k < 32; ++k) {
        wr[k] = w_hh[(size_t)p * GRU_H + k];
        wz[k] = w_hh[(size_t)(GRU_H + p) * GRU_H + k];
        wn[k] = w_hh[(size_t)(2 * GRU_H + p) * GRU_H + k];
    }
    float wir[GRU_D], wiz[GRU_D], win[GRU_D];
#pragma unroll
    for (int d = 0; d < GRU_D; ++d) {
        wir[d] = w_ih[(size_t)p * GRU_D + d];
        wiz[d] = w_ih[(size_t)(GRU_H + p) * GRU_D + d];
        win[d] = w_ih[(size_t)(2 * GRU_H + p) * GRU_D + d];
    }
    const float bR = bias[p];
    const float bZ = bias[GRU_H + p];
    const float bN = bias[2 * GRU_H + p] + bias_n[p];

    float* hw = h2 + 48 * hf + p;
    const float4* hv = (const float4*)(h2 + 48 * hf);
    float* xw = x_lds + XPAD * hf;
    const float* xr = x_lds + XPAD * hf;
    float* osw = out_stage + 32 * hf;
    const bool cap = (lane & 47) == 0;

    float h = 0.0f;
    *hw = 0.0f;
    float xa = xp[p], xb = xp[32 + p], xc = xp[64 + p];

    for (int c = 0; c < GRU_T / CHUNK; ++c) {
        xw[p] = xa; xw[32 + p] = xb; xw[64 + p] = xc;
        if (c + 1 < GRU_T / CHUNK) {
            const size_t nb = (size_t)(c + 1) * (CHUNK * GRU_D);
            xa = xp[nb + p]; xb = xp[nb + 32 + p]; xc = xp[nb + 64 + p];
        }
#pragma unroll 8
        for (int s = 0; s < CHUNK; ++s) {
            const float x0 = xr[3 * s + 0];
            const float x1 = xr[3 * s + 1];
            const float x2 = xr[3 * s + 2];
            float4 hk[8];
#pragma unroll
            for (int q = 0; q < 8; ++q) hk[q] = hv[q];

            const float aR = fmaf(wir[2], x2, fmaf(wir[1], x1, fmaf(wir[0], x0, bR)));
            const float aZ = fmaf(wiz[2], x2, fmaf(wiz[1], x1, fmaf(wiz[0], x0, bZ)));
            const float aN = fmaf(win[2], x2, fmaf(win[1], x1, fmaf(win[0], x0, bN)));

            float r0 = aR, r1 = 0.f, z0 = aZ, z1 = 0.f, n0 = 0.f, n1 = 0.f;
#pragma unroll
            for (int q = 0; q < 8; ++q) {
                const float4 v = hk[q];
                r0 = fmaf(wr[4*q+0], v.x, r0); r1 = fmaf(wr[4*q+1], v.y, r1);
                r0 = fmaf(wr[4*q+2], v.z, r0); r1 = fmaf(wr[4*q+3], v.w, r1);
                z0 = fmaf(wz[4*q+0], v.x, z0); z1 = fmaf(wz[4*q+1], v.y, z1);
                z0 = fmaf(wz[4*q+2], v.z, z0); z1 = fmaf(wz[4*q+3], v.w, z1);
                n0 = fmaf(wn[4*q+0], v.x, n0); n1 = fmaf(wn[4*q+1], v.y, n1);
                n0 = fmaf(wn[4*q+2], v.z, n0); n1 = fmaf(wn[4*q+3], v.w, n1);
            }
            const float rg = fast_sigmoid(r0 + r1);
            const float zg = fast_sigmoid(z0 + z1);
            const float ng = fast_tanh(fmaf(rg, n0 + n1, aN));
            h = fmaf(zg, h - ng, ng);
            if (cap) osw[s] = h;
            *hw = h;
        }
        const float ov = osw[p];
        ob[c * CHUNK + p] = ov;
    }
}

__global__ __launch_bounds__(64, 1) void gru_scan_kernel(
    const float* __restrict__ inp, const float* __restrict__ w_ih,
    const float* __restrict__ w_hh, const float* __restrict__ bias,
    const float* __restrict__ bias_n, float* __restrict__ out)
{
    __shared__ __align__(16) float x_lds[2 * XPAD];       // per-seq x chunk
    __shared__ __align__(16) float out_stage[2 * CHUNK];  // fallback only
    __shared__ __align__(16) float h2[80];                // fallback only

    const int lane = threadIdx.x;            // 0..63
    const int hf   = (lane >> 4) & 1;        // seq select (bit4)
    const int p    = (lane & 15) + 16 * (lane >> 5);  // owned unit / IO idx
    const size_t seq = 2 * (size_t)blockIdx.x + hf;

    const float* xp = inp + seq * (size_t)(GRU_T * GRU_D);
    float*       ob = out + seq * (size_t)GRU_T;
    const int a16 = (lane ^ 16) << 2;

    // ---- one-time probes (ballot-verified, wave-uniform) ----
    int dir = 0;
    bool ok32 = false, sel32 = false, ok16 = false, sel16 = false;
    {
        const int li = lane & 15;
        const int d1 = __builtin_amdgcn_update_dpp(0, li, 0x121, 0xF, 0xF, false);
        if (__ballot(d1 == ((li + 1) & 15)) == ~0ULL)       dir = 1;
        else if (__ballot(d1 == ((li + 15) & 15)) == ~0ULL) dir = -1;

        const unsigned ul = (unsigned)lane;
        uint2v q = __builtin_amdgcn_permlane32_swap(ul, ul, false, false);
        const unsigned w32 = ul ^ 32u;
        const bool a = __ballot(q.x == w32) == ~0ULL;
        const bool b = __ballot(q.y == w32) == ~0ULL;
        ok32 = a || b; sel32 = a;

#if HAVE_P16
        uint2v q16 = __builtin_amdgcn_permlane16_swap(ul, ul, false, false);
        const unsigned w16 = ul ^ 16u;
        const bool a16ok = __ballot(q16.x == w16) == ~0ULL;
        const bool b16ok = __ballot(q16.y == w16) == ~0ULL;
        ok16 = a16ok || b16ok; sel16 = a16ok;
#endif
    }

    if (dir != 0 && ok32) {
        if (ok16) {
            if (sel32) gru_fast<true,  true >(xp, ob, w_ih, w_hh, bias, bias_n,
                                              x_lds, lane, hf, p, dir, sel16, a16);
            else       gru_fast<false, true >(xp, ob, w_ih, w_hh, bias, bias_n,
                                              x_lds, lane, hf, p, dir, sel16, a16);
        } else {
            if (sel32) gru_fast<true,  false>(xp, ob, w_ih, w_hh, bias, bias_n,
                                              x_lds, lane, hf, p, dir, sel16, a16);
            else       gru_fast<false, false>(xp, ob, w_ih, w_hh, bias, bias_n,
                                              x_lds, lane, hf, p, dir, sel16, a16);
        }
    } else {
        gru_lds(xp, ob, w_ih, w_hh, bias, bias_n,
                x_lds, out_stage, h2, lane, hf, p);
    }
}

extern "C" void kernel_launch(void* const* d_in, const int* in_sizes, int n_in,
                              void* d_out, int out_size, void* d_ws, size_t ws_size,
                              hipStream_t stream) {
    const float* inp    = (const float*)d_in[0];
    const float* w_ih   = (const float*)d_in[1];
    const float* w_hh   = (const float*)d_in[2];
    const float* bias   = (const float*)d_in[3];
    const float* bias_n = (const float*)d_in[4];
    float* out = (float*)d_out;

    dim3 grid(GRU_B / 2);
    dim3 block(64);
    gru_scan_kernel<<<grid, block, 0, stream>>>(inp, w_ih, w_hh, bias, bias_n, out);
}